// Round 7
// baseline (316.454 us; speedup 1.0000x reference)
//
#include <hip/hip_runtime.h>

// ---------- constants for this problem ----------
#define BATCH 2
#define NTOK 2048          // image tokens per batch
#define MTOK 256           // text tokens per batch
#define CDIM 1024
#define NHEAD 16
#define HD 64
#define SEQ (NTOK + MTOK)  // 2304
#define TOK_X (BATCH * NTOK)   // 4096
#define TOK_Y (BATCH * MTOK)   // 512
#define BHN (BATCH * NHEAD)    // 32
#define NKT (SEQ / 64)         // 36 KV tiles (even -> unroll-2 safe)
#define QKV_BLOCKS 1536        // (3*CDIM/64) * (TOK_X/128) = 48*32
#define KV_BLOCKS 128          // (2*CDIM/64) * (TOK_Y/128) = 32*4

typedef __attribute__((ext_vector_type(8))) short bf16x8;
typedef __attribute__((ext_vector_type(4))) short bf16x4;
typedef __attribute__((ext_vector_type(4))) float f32x4;
typedef __attribute__((ext_vector_type(2))) unsigned int u32x2;
typedef __attribute__((ext_vector_type(4))) unsigned int u32x4;
#if __has_builtin(__builtin_amdgcn_cvt_pk_bf16_f32)
typedef __attribute__((ext_vector_type(2))) __bf16 bf16x2_t;
#endif

__device__ __forceinline__ float b2f(ushort u) {
    unsigned v = ((unsigned)u) << 16;
    return __builtin_bit_cast(float, v);
}
__device__ __forceinline__ ushort f2b(float f) {
    unsigned u = __builtin_bit_cast(unsigned, f);
    u += 0x7fffu + ((u >> 16) & 1u);   // round-to-nearest-even
    return (ushort)(u >> 16);
}
__device__ __forceinline__ unsigned pack2bf(float a, float b) {
#if __has_builtin(__builtin_amdgcn_cvt_pk_bf16_f32)
    bf16x2_t h = __builtin_amdgcn_cvt_pk_bf16_f32(a, b);   // lo=a, hi=b
    return __builtin_bit_cast(unsigned, h);
#else
    return ((unsigned)f2b(b) << 16) | (unsigned)f2b(a);
#endif
}

// async 16B global -> LDS; LDS dest = wave-uniform base, HW scatters lane*16B
__device__ __forceinline__ void async_load16(const ushort* g, ushort* l) {
    __builtin_amdgcn_global_load_lds(
        (const __attribute__((address_space(1))) unsigned*)(const void*)g,
        (__attribute__((address_space(3))) unsigned*)(void*)l, 16, 0, 0);
}

// ---------- one merged cast kernel: 5 fp32->bf16 segments ----------
__global__ __launch_bounds__(256) void cast_all(
    const float* __restrict__ s0, ushort* __restrict__ t0, int b0,
    const float* __restrict__ s1, ushort* __restrict__ t1, int b1,
    const float* __restrict__ s2, ushort* __restrict__ t2, int b2,
    const float* __restrict__ s3, ushort* __restrict__ t3, int b3,
    const float* __restrict__ s4, ushort* __restrict__ t4) {
    int blk = blockIdx.x;
    const float* s; ushort* t;
    if (blk < b0)      { s = s0; t = t0; }
    else if (blk < b1) { s = s1; t = t1; blk -= b0; }
    else if (blk < b2) { s = s2; t = t2; blk -= b1; }
    else if (blk < b3) { s = s3; t = t3; blk -= b2; }
    else               { s = s4; t = t4; blk -= b3; }
    int i = (blk * 256 + threadIdx.x) * 8;
    float4 a = *(const float4*)(s + i);
    float4 b = *(const float4*)(s + i + 4);
    ushort tmp[8] = {f2b(a.x), f2b(a.y), f2b(a.z), f2b(a.w),
                     f2b(b.x), f2b(b.y), f2b(b.z), f2b(b.w)};
    *(uint4*)(t + i) = *(const uint4*)tmp;
}

// ---------- merged qkv+kv GEMM, 128x64 tiles, one launch (1664 blocks) ----------
// R16: tile 128(M)x64(N), 4 waves x (32x64), acc[2][4], LDS 24 KB -> 5-6
// blocks/CU co-resident (vs 2-3 at 128x128): the K-loop is latency-bound
// (load -> barrier -> compute, 16 iters), more co-resident blocks = overlap.
// One head per block (N-tile = 64 = one head's d range). Epilogue: bias +
// rmsnorm(q,k) + scatter q->qh, k->kc, V directly into pair-interleaved vt.
__global__ __launch_bounds__(256) void gemm_qkvkv(const ushort* __restrict__ Aq,
                                                  const ushort* __restrict__ Wq,
                                                  const float* __restrict__ bq,
                                                  const ushort* __restrict__ Ak,
                                                  const ushort* __restrict__ Wk,
                                                  const float* __restrict__ bk,
                                                  ushort* __restrict__ d_q,
                                                  ushort* __restrict__ d_k,
                                                  ushort* __restrict__ d_vt,
                                                  const float* __restrict__ qn_w,
                                                  const float* __restrict__ kn_w) {
    __shared__ ushort As[128][64];   // 16 KB
    __shared__ ushort Bs[64][64];    // 8 KB
    int tid = threadIdx.x;
    int lane = tid & 63;
    int w = tid >> 6;
    int wm = w * 32;
    int l15 = lane & 15;
    int quad = lane >> 4;
    int sw = l15 & 7;

    int blk = blockIdx.x;
    int mode, bx, by;
    const ushort *A, *Bt;
    const float* bias;
    if (blk < QKV_BLOCKS) {
        mode = 1;
        int xcd = blk & 7;
        int loc = blk >> 3;         // 0..191
        by = xcd * 4 + (loc & 3);   // 0..31: each XCD a contiguous 4-row M strip
        bx = loc >> 2;              // 0..47
        A = Aq; Bt = Wq; bias = bq;
    } else {
        mode = 2;
        int loc = blk - QKV_BLOCKS; // 0..127
        bx = loc & 31;              // 0..31
        by = loc >> 5;              // 0..3
        A = Ak; Bt = Wk; bias = bk;
    }
    int bm = by * 128;
    int bn = bx * 64;

    f32x4 acc[2][4];
#pragma unroll
    for (int i = 0; i < 2; i++)
#pragma unroll
        for (int j = 0; j < 4; j++) acc[i][j] = (f32x4)0.0f;

    int lrow = lane >> 3;
    int lcol = ((lane & 7) ^ lrow) * 8;

    for (int k0 = 0; k0 < CDIM; k0 += 64) {
        __syncthreads();
#pragma unroll
        for (int p = 0; p < 4; p++) {
            int rb = w * 32 + p * 8;
            async_load16(&A[(size_t)(bm + rb + lrow) * CDIM + k0 + lcol], &As[rb][0]);
        }
#pragma unroll
        for (int p = 0; p < 2; p++) {
            int rb = w * 16 + p * 8;
            async_load16(&Bt[(size_t)(bn + rb + lrow) * CDIM + k0 + lcol], &Bs[rb][0]);
        }
        __syncthreads();
#pragma unroll
        for (int kk = 0; kk < 64; kk += 32) {
            bf16x8 af[2], bfr[4];
            int g = (kk >> 3) + quad;
            int csw = (g ^ sw) * 8;
#pragma unroll
            for (int i = 0; i < 2; i++)
                af[i] = *(const bf16x8*)&As[wm + i * 16 + l15][csw];
#pragma unroll
            for (int j = 0; j < 4; j++)
                bfr[j] = *(const bf16x8*)&Bs[j * 16 + l15][csw];
#pragma unroll
            for (int i = 0; i < 2; i++)
#pragma unroll
                for (int j = 0; j < 4; j++)
                    acc[i][j] = __builtin_amdgcn_mfma_f32_16x16x32_bf16(af[i], bfr[j], acc[i][j], 0, 0, 0);
        }
    }

    float bv[4];
#pragma unroll
    for (int j = 0; j < 4; j++) bv[j] = bias[bn + j * 16 + l15];
#pragma unroll
    for (int i = 0; i < 2; i++)
#pragma unroll
        for (int j = 0; j < 4; j++)
#pragma unroll
            for (int r = 0; r < 4; r++) acc[i][j][r] += bv[j];

    int region = bn >> 10;
    int h = (bn >> 6) & (NHEAD - 1);
    bool is_q = (mode == 1) && (region == 0);
    bool is_k = (mode == 1) ? (region == 1) : (region == 0);
    if (is_q || is_k) {
        const float* wv = is_q ? qn_w : kn_w;
        float wj[4];
#pragma unroll
        for (int j = 0; j < 4; j++) wj[j] = wv[j * 16 + l15];
        float qs = is_q ? (0.125f * 1.44269504088896f) : 1.0f;
#pragma unroll
        for (int i = 0; i < 2; i++)
#pragma unroll
            for (int r = 0; r < 4; r++) {
                float s = acc[i][0][r] * acc[i][0][r] + acc[i][1][r] * acc[i][1][r]
                        + acc[i][2][r] * acc[i][2][r] + acc[i][3][r] * acc[i][3][r];
                s += __shfl_xor(s, 1);
                s += __shfl_xor(s, 2);
                s += __shfl_xor(s, 4);
                s += __shfl_xor(s, 8);
                float rs = rsqrtf(s * (1.0f / 64.0f) + 1e-6f) * qs;
#pragma unroll
                for (int j = 0; j < 4; j++) acc[i][j][r] *= rs * wj[j];
            }
    }
    size_t l15seq = (size_t)l15 * SEQ;   // for v scatter
#pragma unroll
    for (int i = 0; i < 2; i++) {
#pragma unroll
        for (int r = 0; r < 4; r++) {
            int t = bm + wm + i * 16 + quad * 4 + r;   // token row
            int b, s;
            if (mode == 1) { b = t >> 11; s = t & (NTOK - 1); }
            else           { b = t >> 8;  s = NTOK + (t & (MTOK - 1)); }
            size_t bh = (size_t)(b * NHEAD + h);
            if (is_q) {
                size_t base = (bh * NTOK + s) * 64;
#pragma unroll
                for (int j = 0; j < 4; j++)
                    d_q[base + j * 16 + l15] = f2b(acc[i][j][r]);
            } else if (is_k) {
                size_t base = (bh * SEQ + s) * 64;
#pragma unroll
                for (int j = 0; j < 4; j++)
                    d_k[base + j * 16 + l15] = f2b(acc[i][j][r]);
            } else {
                // V -> vt [bh][d][pair-interleaved seq]
                int within = s & 31;
                int pos = ((s >> 5) << 5) + ((within & 15) << 1) + (within >> 4);
                size_t base = bh * 64 * SEQ + l15seq + pos;
#pragma unroll
                for (int j = 0; j < 4; j++)
                    d_vt[base + (size_t)(j * 16) * SEQ] = f2b(acc[i][j][r]);
            }
        }
    }
}

// ---------- proj GEMM: 128x64 tiles, fp32 out + bias (XCD-swizzled grid 512) ----------
__global__ __launch_bounds__(256) void gemm_proj(const ushort* __restrict__ A,
                                                 const ushort* __restrict__ Bt,
                                                 const float* __restrict__ bias,
                                                 float* __restrict__ Cf) {
    __shared__ ushort As[128][64];
    __shared__ ushort Bs[64][64];
    int tid = threadIdx.x;
    int lane = tid & 63;
    int w = tid >> 6;
    int wm = w * 32;
    int l15 = lane & 15;
    int quad = lane >> 4;
    int sw = l15 & 7;
    int xcd = blockIdx.x & 7;
    int loc = blockIdx.x >> 3;      // 0..63
    int by = xcd * 4 + (loc & 3);   // 0..31
    int bx = loc >> 2;              // 0..15
    int bm = by * 128;
    int bn = bx * 64;

    f32x4 acc[2][4];
#pragma unroll
    for (int i = 0; i < 2; i++)
#pragma unroll
        for (int j = 0; j < 4; j++) acc[i][j] = (f32x4)0.0f;

    int lrow = lane >> 3;
    int lcol = ((lane & 7) ^ lrow) * 8;

    for (int k0 = 0; k0 < CDIM; k0 += 64) {
        __syncthreads();
#pragma unroll
        for (int p = 0; p < 4; p++) {
            int rb = w * 32 + p * 8;
            async_load16(&A[(size_t)(bm + rb + lrow) * CDIM + k0 + lcol], &As[rb][0]);
        }
#pragma unroll
        for (int p = 0; p < 2; p++) {
            int rb = w * 16 + p * 8;
            async_load16(&Bt[(size_t)(bn + rb + lrow) * CDIM + k0 + lcol], &Bs[rb][0]);
        }
        __syncthreads();
#pragma unroll
        for (int kk = 0; kk < 64; kk += 32) {
            bf16x8 af[2], bfr[4];
            int g = (kk >> 3) + quad;
            int csw = (g ^ sw) * 8;
#pragma unroll
            for (int i = 0; i < 2; i++)
                af[i] = *(const bf16x8*)&As[wm + i * 16 + l15][csw];
#pragma unroll
            for (int j = 0; j < 4; j++)
                bfr[j] = *(const bf16x8*)&Bs[j * 16 + l15][csw];
#pragma unroll
            for (int i = 0; i < 2; i++)
#pragma unroll
                for (int j = 0; j < 4; j++)
                    acc[i][j] = __builtin_amdgcn_mfma_f32_16x16x32_bf16(af[i], bfr[j], acc[i][j], 0, 0, 0);
        }
    }
#pragma unroll
    for (int i = 0; i < 2; i++) {
        int row0 = bm + wm + i * 16 + quad * 4;
#pragma unroll
        for (int j = 0; j < 4; j++) {
            int col = bn + j * 16 + l15;
            float bvv = bias[col];
#pragma unroll
            for (int r = 0; r < 4; r++)
                Cf[(size_t)(row0 + r) * CDIM + col] = acc[i][j][r] + bvv;
        }
    }
}

// ---------- flash attention: 16 q/wave, 8 waves/block, 64-key dbuf tiles ----------
// R4: 16q/wave, 512-thr blocks -> 4 waves/SIMD (67.1 us, occ 34.7%).
// R5: VALU address-calc elimination. Counters: MfmaUtil 23 / VALUBusy 47 /
// LDS ~26% / HBM 16% -> no pipe saturated, issue-overhead bound. The 18
// LDS ops per tile each recomputed addresses from runtime parity p=t&1
// (m33-class VALU tax). Fix: unroll KV loop by 2 (parity compile-time),
// one lane-fixed base pointer per LDS array, all ds_read/ds_write become
// base + imm offset (max 16.2KB < 64KB). Sync discipline identical to the
// proven double-buffer scheme; NKT=36 even.
__global__ __launch_bounds__(512) void attn_fwd(const ushort* __restrict__ qh,
                                                const ushort* __restrict__ kc,
                                                const ushort* __restrict__ vt,
                                                ushort* __restrict__ out) {
    __shared__ ushort Ks[2][64][72];   // [buf][key][d]
    __shared__ ushort Vs[2][64][68];   // [buf][d][key-interleaved]
    int tid = threadIdx.x;
    int lane = tid & 63;
    int w = tid >> 6;                  // 0..7
    int l15 = lane & 15;
    int quad = lane >> 4;
    int bh = blockIdx.y;
    int q0 = blockIdx.x * 128 + w * 16;

    const ushort* qp = qh + ((size_t)bh * NTOK + q0 + l15) * 64 + quad * 8;
    bf16x8 qA0 = *(const bf16x8*)qp;
    bf16x8 qA1 = *(const bf16x8*)(qp + 32);

    float lA = 0.0f;
    f32x4 OA[4];
#pragma unroll
    for (int jd = 0; jd < 4; jd++) OA[jd] = (f32x4)0.0f;

    int sr = tid >> 3;                 // 0..63: full K/V row range with 512 thr
    int sc = (tid & 7) * 8;
    const ushort* kp = kc + (size_t)bh * SEQ * 64 + (size_t)sr * 64 + sc;
    const ushort* vp = vt + (size_t)bh * 64 * SEQ + (size_t)sr * SEQ + sc;

    // lane-fixed LDS base pointers; buffer parity & subtile offsets are
    // compile-time immediates after the unroll-2 below.
    const ushort* krb = &Ks[0][l15][quad * 8];
    const ushort* vrb = &Vs[0][l15][quad * 8];
    ushort* kwb = &Ks[0][sr][sc];
    ushort* vwb = &Vs[0][sr][sc];
#define KS_STRIDE (64 * 72)
#define VS_STRIDE (64 * 68)

    // prefetch tile 0 into registers
    uint4 rk = *(const uint4*)kp;
    uint4 rv = *(const uint4*)vp;

#define ATT_STAGE(P) { \
    *(uint4*)(kwb + (P) * KS_STRIDE) = rk; \
    *(uint4*)(vwb + (P) * VS_STRIDE) = rv; }

#define ATT_ADV() { \
    kp += 64 * 64; vp += 64; \
    rk = *(const uint4*)kp; \
    rv = *(const uint4*)vp; }

#define ATT_COMPUTE(P) { \
    f32x4 SA[4]; \
    _Pragma("unroll") for (int j = 0; j < 4; j++) SA[j] = (f32x4)0.0f; \
    __builtin_amdgcn_s_setprio(1); \
    _Pragma("unroll") for (int j = 0; j < 4; j++) { \
        bf16x8 kf = *(const bf16x8*)(krb + (P) * KS_STRIDE + j * (16 * 72)); \
        SA[j] = __builtin_amdgcn_mfma_f32_16x16x32_bf16(kf, qA0, SA[j], 0, 0, 0); } \
    _Pragma("unroll") for (int j = 0; j < 4; j++) { \
        bf16x8 kf = *(const bf16x8*)(krb + (P) * KS_STRIDE + j * (16 * 72) + 32); \
        SA[j] = __builtin_amdgcn_mfma_f32_16x16x32_bf16(kf, qA1, SA[j], 0, 0, 0); } \
    __builtin_amdgcn_s_setprio(0); \
    _Pragma("unroll") for (int pb2 = 0; pb2 < 2; pb2++) { \
        int j0 = 2 * pb2, j1 = j0 + 1; \
        u32x4 wa; \
        _Pragma("unroll") for (int r = 0; r < 4; r++) { \
            float a0 = __builtin_amdgcn_exp2f(SA[j0][r]); \
            float a1 = __builtin_amdgcn_exp2f(SA[j1][r]); \
            lA += a0 + a1; \
            wa[r] = pack2bf(a0, a1); } \
        bf16x8 pA = __builtin_bit_cast(bf16x8, wa); \
        __builtin_amdgcn_s_setprio(1); \
        _Pragma("unroll") for (int jd = 0; jd < 4; jd++) { \
            bf16x8 vf = *(const bf16x8*)(vrb + (P) * VS_STRIDE + jd * (16 * 68) + pb2 * 32); \
            OA[jd] = __builtin_amdgcn_mfma_f32_16x16x32_bf16(vf, pA, OA[jd], 0, 0, 0); } \
        __builtin_amdgcn_s_setprio(0); } }

    for (int tt = 0; tt < NKT; tt += 2) {
        // ---- tile tt (buffer 0) ----
        ATT_STAGE(0);
        __syncthreads();
        ATT_ADV();                    // tile tt+1 -> regs (NKT even: always valid)
        ATT_COMPUTE(0);
        // ---- tile tt+1 (buffer 1) ----
        ATT_STAGE(1);
        __syncthreads();
        if (tt + 2 < NKT) ATT_ADV();  // tile tt+2 -> regs
        ATT_COMPUTE(1);
    }

    lA += __shfl_xor(lA, 16);
    lA += __shfl_xor(lA, 32);
    float invA = 1.0f / lA;
    int b = bh >> 4, h = bh & 15;
    int tokA = (b << 11) + q0 + l15;
    ushort* obaseA = out + ((size_t)tokA * NHEAD + h) * 64;
#pragma unroll
    for (int jd = 0; jd < 4; jd++) {
        u32x2 pk;
        pk.x = pack2bf(OA[jd][0] * invA, OA[jd][1] * invA);
        pk.y = pack2bf(OA[jd][2] * invA, OA[jd][3] * invA);
        *(u32x2*)&obaseA[jd * 16 + quad * 4] = pk;
    }
}

// ---------- launch ----------
extern "C" void kernel_launch(void* const* d_in, const int* in_sizes, int n_in,
                              void* d_out, int out_size, void* d_ws, size_t ws_size,
                              hipStream_t stream) {
    const float* x      = (const float*)d_in[0];
    const float* y      = (const float*)d_in[1];
    const float* qkv_w  = (const float*)d_in[2];
    const float* qkv_b  = (const float*)d_in[3];
    const float* kv_w   = (const float*)d_in[4];
    const float* kv_b   = (const float*)d_in[5];
    const float* qn_w   = (const float*)d_in[6];
    const float* kn_w   = (const float*)d_in[7];
    const float* proj_w = (const float*)d_in[8];
    const float* proj_b = (const float*)d_in[9];
    float* outp = (float*)d_out;

    char* ws = (char*)d_ws;
    ushort* x_bf    = (ushort*)ws; ws += (size_t)TOK_X * CDIM * 2;
    ushort* y_bf    = (ushort*)ws; ws += (size_t)TOK_Y * CDIM * 2;
    ushort* qkvw_bf = (ushort*)ws; ws += (size_t)3 * CDIM * CDIM * 2;
    ushort* kvw_bf  = (ushort*)ws; ws += (size_t)2 * CDIM * CDIM * 2;
    ushort* projw_bf= (ushort*)ws; ws += (size_t)CDIM * CDIM * 2;
    ushort* qh      = (ushort*)ws; ws += (size_t)BHN * NTOK * 64 * 2;
    ushort* kc      = (ushort*)ws; ws += (size_t)BHN * SEQ * 64 * 2;
    ushort* vt      = (ushort*)ws; ws += (size_t)BHN * SEQ * 64 * 2;
    ushort* ao      = (ushort*)ws; ws += (size_t)TOK_X * CDIM * 2;

    int c0 = TOK_X * CDIM / 2048;
    int c1 = c0 + TOK_Y * CDIM / 2048;
    int c2 = c1 + 3 * CDIM * CDIM / 2048;
    int c3 = c2 + 2 * CDIM * CDIM / 2048;
    int c4 = c3 + CDIM * CDIM / 2048;
    cast_all<<<c4, 256, 0, stream>>>(x, x_bf, c0, y, y_bf, c1, qkv_w, qkvw_bf, c2,
                                     kv_w, kvw_bf, c3, proj_w, projw_bf);

    gemm_qkvkv<<<QKV_BLOCKS + KV_BLOCKS, 256, 0, stream>>>(
        x_bf, qkvw_bf, qkv_b, y_bf, kvw_bf, kv_b, qh, kc, vt, qn_w, kn_w);

    attn_fwd<<<dim3(NTOK / 128, BHN), 512, 0, stream>>>(qh, kc, vt, ao);

    gemm_proj<<<512, 256, 0, stream>>>(ao, projw_bf, proj_b, outp);
}

// Round 10
// 217.863 us; speedup vs baseline: 1.4525x; 1.4525x over previous
//
#include <hip/hip_runtime.h>

// ---------- constants for this problem ----------
#define BATCH 2
#define NTOK 2048          // image tokens per batch
#define MTOK 256           // text tokens per batch
#define CDIM 1024
#define NHEAD 16
#define HD 64
#define SEQ (NTOK + MTOK)  // 2304
#define TOK_X (BATCH * NTOK)   // 4096
#define TOK_Y (BATCH * MTOK)   // 512
#define BHN (BATCH * NHEAD)    // 32
#define NKT (SEQ / 64)         // 36 KV tiles (even -> unroll-2 safe)
#define QKV_BLOCKS 1536        // (3*CDIM/64) * (TOK_X/128) = 48*32
#define KV_BLOCKS 128          // (2*CDIM/64) * (TOK_Y/128) = 32*4

typedef __attribute__((ext_vector_type(8))) short bf16x8;
typedef __attribute__((ext_vector_type(4))) short bf16x4;
typedef __attribute__((ext_vector_type(4))) float f32x4;
typedef __attribute__((ext_vector_type(2))) unsigned int u32x2;
typedef __attribute__((ext_vector_type(4))) unsigned int u32x4;
#if __has_builtin(__builtin_amdgcn_cvt_pk_bf16_f32)
typedef __attribute__((ext_vector_type(2))) __bf16 bf16x2_t;
#endif

__device__ __forceinline__ float b2f(ushort u) {
    unsigned v = ((unsigned)u) << 16;
    return __builtin_bit_cast(float, v);
}
__device__ __forceinline__ ushort f2b(float f) {
    unsigned u = __builtin_bit_cast(unsigned, f);
    u += 0x7fffu + ((u >> 16) & 1u);   // round-to-nearest-even
    return (ushort)(u >> 16);
}
__device__ __forceinline__ unsigned pack2bf(float a, float b) {
#if __has_builtin(__builtin_amdgcn_cvt_pk_bf16_f32)
    bf16x2_t h = __builtin_amdgcn_cvt_pk_bf16_f32(a, b);   // lo=a, hi=b
    return __builtin_bit_cast(unsigned, h);
#else
    return ((unsigned)f2b(b) << 16) | (unsigned)f2b(a);
#endif
}

// async 16B global -> LDS; LDS dest = wave-uniform base, HW scatters lane*16B
__device__ __forceinline__ void async_load16(const ushort* g, ushort* l) {
    __builtin_amdgcn_global_load_lds(
        (const __attribute__((address_space(1))) unsigned*)(const void*)g,
        (__attribute__((address_space(3))) unsigned*)(void*)l, 16, 0, 0);
}

// ---------- one merged cast kernel: 5 fp32->bf16 segments ----------
__global__ __launch_bounds__(256) void cast_all(
    const float* __restrict__ s0, ushort* __restrict__ t0, int b0,
    const float* __restrict__ s1, ushort* __restrict__ t1, int b1,
    const float* __restrict__ s2, ushort* __restrict__ t2, int b2,
    const float* __restrict__ s3, ushort* __restrict__ t3, int b3,
    const float* __restrict__ s4, ushort* __restrict__ t4) {
    int blk = blockIdx.x;
    const float* s; ushort* t;
    if (blk < b0)      { s = s0; t = t0; }
    else if (blk < b1) { s = s1; t = t1; blk -= b0; }
    else if (blk < b2) { s = s2; t = t2; blk -= b1; }
    else if (blk < b3) { s = s3; t = t3; blk -= b2; }
    else               { s = s4; t = t4; blk -= b3; }
    int i = (blk * 256 + threadIdx.x) * 8;
    float4 a = *(const float4*)(s + i);
    float4 b = *(const float4*)(s + i + 4);
    ushort tmp[8] = {f2b(a.x), f2b(a.y), f2b(a.z), f2b(a.w),
                     f2b(b.x), f2b(b.y), f2b(b.z), f2b(b.w)};
    *(uint4*)(t + i) = *(const uint4*)tmp;
}

// ---------- merged qkv+kv GEMM, 128x64 tiles, one launch (1664 blocks) ----------
// R16: tile 128(M)x64(N), 4 waves x (32x64), acc[2][4], LDS 24 KB -> 5-6
// blocks/CU co-resident (vs 2-3 at 128x128): the K-loop is latency-bound
// (load -> barrier -> compute, 16 iters), more co-resident blocks = overlap.
// One head per block (N-tile = 64 = one head's d range). Epilogue: bias +
// rmsnorm(q,k) + scatter q->qh, k->kc, V directly into pair-interleaved vt.
__global__ __launch_bounds__(256) void gemm_qkvkv(const ushort* __restrict__ Aq,
                                                  const ushort* __restrict__ Wq,
                                                  const float* __restrict__ bq,
                                                  const ushort* __restrict__ Ak,
                                                  const ushort* __restrict__ Wk,
                                                  const float* __restrict__ bk,
                                                  ushort* __restrict__ d_q,
                                                  ushort* __restrict__ d_k,
                                                  ushort* __restrict__ d_vt,
                                                  const float* __restrict__ qn_w,
                                                  const float* __restrict__ kn_w) {
    __shared__ ushort As[128][64];   // 16 KB
    __shared__ ushort Bs[64][64];    // 8 KB
    int tid = threadIdx.x;
    int lane = tid & 63;
    int w = tid >> 6;
    int wm = w * 32;
    int l15 = lane & 15;
    int quad = lane >> 4;
    int sw = l15 & 7;

    int blk = blockIdx.x;
    int mode, bx, by;
    const ushort *A, *Bt;
    const float* bias;
    if (blk < QKV_BLOCKS) {
        mode = 1;
        int xcd = blk & 7;
        int loc = blk >> 3;         // 0..191
        by = xcd * 4 + (loc & 3);   // 0..31: each XCD a contiguous 4-row M strip
        bx = loc >> 2;              // 0..47
        A = Aq; Bt = Wq; bias = bq;
    } else {
        mode = 2;
        int loc = blk - QKV_BLOCKS; // 0..127
        bx = loc & 31;              // 0..31
        by = loc >> 5;              // 0..3
        A = Ak; Bt = Wk; bias = bk;
    }
    int bm = by * 128;
    int bn = bx * 64;

    f32x4 acc[2][4];
#pragma unroll
    for (int i = 0; i < 2; i++)
#pragma unroll
        for (int j = 0; j < 4; j++) acc[i][j] = (f32x4)0.0f;

    int lrow = lane >> 3;
    int lcol = ((lane & 7) ^ lrow) * 8;

    for (int k0 = 0; k0 < CDIM; k0 += 64) {
        __syncthreads();
#pragma unroll
        for (int p = 0; p < 4; p++) {
            int rb = w * 32 + p * 8;
            async_load16(&A[(size_t)(bm + rb + lrow) * CDIM + k0 + lcol], &As[rb][0]);
        }
#pragma unroll
        for (int p = 0; p < 2; p++) {
            int rb = w * 16 + p * 8;
            async_load16(&Bt[(size_t)(bn + rb + lrow) * CDIM + k0 + lcol], &Bs[rb][0]);
        }
        __syncthreads();
#pragma unroll
        for (int kk = 0; kk < 64; kk += 32) {
            bf16x8 af[2], bfr[4];
            int g = (kk >> 3) + quad;
            int csw = (g ^ sw) * 8;
#pragma unroll
            for (int i = 0; i < 2; i++)
                af[i] = *(const bf16x8*)&As[wm + i * 16 + l15][csw];
#pragma unroll
            for (int j = 0; j < 4; j++)
                bfr[j] = *(const bf16x8*)&Bs[j * 16 + l15][csw];
#pragma unroll
            for (int i = 0; i < 2; i++)
#pragma unroll
                for (int j = 0; j < 4; j++)
                    acc[i][j] = __builtin_amdgcn_mfma_f32_16x16x32_bf16(af[i], bfr[j], acc[i][j], 0, 0, 0);
        }
    }

    float bv[4];
#pragma unroll
    for (int j = 0; j < 4; j++) bv[j] = bias[bn + j * 16 + l15];
#pragma unroll
    for (int i = 0; i < 2; i++)
#pragma unroll
        for (int j = 0; j < 4; j++)
#pragma unroll
            for (int r = 0; r < 4; r++) acc[i][j][r] += bv[j];

    int region = bn >> 10;
    int h = (bn >> 6) & (NHEAD - 1);
    bool is_q = (mode == 1) && (region == 0);
    bool is_k = (mode == 1) ? (region == 1) : (region == 0);
    if (is_q || is_k) {
        const float* wv = is_q ? qn_w : kn_w;
        float wj[4];
#pragma unroll
        for (int j = 0; j < 4; j++) wj[j] = wv[j * 16 + l15];
        float qs = is_q ? (0.125f * 1.44269504088896f) : 1.0f;
#pragma unroll
        for (int i = 0; i < 2; i++)
#pragma unroll
            for (int r = 0; r < 4; r++) {
                float s = acc[i][0][r] * acc[i][0][r] + acc[i][1][r] * acc[i][1][r]
                        + acc[i][2][r] * acc[i][2][r] + acc[i][3][r] * acc[i][3][r];
                s += __shfl_xor(s, 1);
                s += __shfl_xor(s, 2);
                s += __shfl_xor(s, 4);
                s += __shfl_xor(s, 8);
                float rs = rsqrtf(s * (1.0f / 64.0f) + 1e-6f) * qs;
#pragma unroll
                for (int j = 0; j < 4; j++) acc[i][j][r] *= rs * wj[j];
            }
    }
    size_t l15seq = (size_t)l15 * SEQ;   // for v scatter
#pragma unroll
    for (int i = 0; i < 2; i++) {
#pragma unroll
        for (int r = 0; r < 4; r++) {
            int t = bm + wm + i * 16 + quad * 4 + r;   // token row
            int b, s;
            if (mode == 1) { b = t >> 11; s = t & (NTOK - 1); }
            else           { b = t >> 8;  s = NTOK + (t & (MTOK - 1)); }
            size_t bh = (size_t)(b * NHEAD + h);
            if (is_q) {
                size_t base = (bh * NTOK + s) * 64;
#pragma unroll
                for (int j = 0; j < 4; j++)
                    d_q[base + j * 16 + l15] = f2b(acc[i][j][r]);
            } else if (is_k) {
                size_t base = (bh * SEQ + s) * 64;
#pragma unroll
                for (int j = 0; j < 4; j++)
                    d_k[base + j * 16 + l15] = f2b(acc[i][j][r]);
            } else {
                // V -> vt [bh][d][pair-interleaved seq]
                int within = s & 31;
                int pos = ((s >> 5) << 5) + ((within & 15) << 1) + (within >> 4);
                size_t base = bh * 64 * SEQ + l15seq + pos;
#pragma unroll
                for (int j = 0; j < 4; j++)
                    d_vt[base + (size_t)(j * 16) * SEQ] = f2b(acc[i][j][r]);
            }
        }
    }
}

// ---------- proj GEMM: 128x64 tiles, fp32 out + bias (XCD-swizzled grid 512) ----------
__global__ __launch_bounds__(256) void gemm_proj(const ushort* __restrict__ A,
                                                 const ushort* __restrict__ Bt,
                                                 const float* __restrict__ bias,
                                                 float* __restrict__ Cf) {
    __shared__ ushort As[128][64];
    __shared__ ushort Bs[64][64];
    int tid = threadIdx.x;
    int lane = tid & 63;
    int w = tid >> 6;
    int wm = w * 32;
    int l15 = lane & 15;
    int quad = lane >> 4;
    int sw = l15 & 7;
    int xcd = blockIdx.x & 7;
    int loc = blockIdx.x >> 3;      // 0..63
    int by = xcd * 4 + (loc & 3);   // 0..31
    int bx = loc >> 2;              // 0..15
    int bm = by * 128;
    int bn = bx * 64;

    f32x4 acc[2][4];
#pragma unroll
    for (int i = 0; i < 2; i++)
#pragma unroll
        for (int j = 0; j < 4; j++) acc[i][j] = (f32x4)0.0f;

    int lrow = lane >> 3;
    int lcol = ((lane & 7) ^ lrow) * 8;

    for (int k0 = 0; k0 < CDIM; k0 += 64) {
        __syncthreads();
#pragma unroll
        for (int p = 0; p < 4; p++) {
            int rb = w * 32 + p * 8;
            async_load16(&A[(size_t)(bm + rb + lrow) * CDIM + k0 + lcol], &As[rb][0]);
        }
#pragma unroll
        for (int p = 0; p < 2; p++) {
            int rb = w * 16 + p * 8;
            async_load16(&Bt[(size_t)(bn + rb + lrow) * CDIM + k0 + lcol], &Bs[rb][0]);
        }
        __syncthreads();
#pragma unroll
        for (int kk = 0; kk < 64; kk += 32) {
            bf16x8 af[2], bfr[4];
            int g = (kk >> 3) + quad;
            int csw = (g ^ sw) * 8;
#pragma unroll
            for (int i = 0; i < 2; i++)
                af[i] = *(const bf16x8*)&As[wm + i * 16 + l15][csw];
#pragma unroll
            for (int j = 0; j < 4; j++)
                bfr[j] = *(const bf16x8*)&Bs[j * 16 + l15][csw];
#pragma unroll
            for (int i = 0; i < 2; i++)
#pragma unroll
                for (int j = 0; j < 4; j++)
                    acc[i][j] = __builtin_amdgcn_mfma_f32_16x16x32_bf16(af[i], bfr[j], acc[i][j], 0, 0, 0);
        }
    }
#pragma unroll
    for (int i = 0; i < 2; i++) {
        int row0 = bm + wm + i * 16 + quad * 4;
#pragma unroll
        for (int j = 0; j < 4; j++) {
            int col = bn + j * 16 + l15;
            float bvv = bias[col];
#pragma unroll
            for (int r = 0; r < 4; r++)
                Cf[(size_t)(row0 + r) * CDIM + col] = acc[i][j][r] + bvv;
        }
    }
}

// ---------- flash attention: 16 q/wave, 8 waves/block, 64-key dbuf tiles ----------
// R4 (67.1 us): 16q/wave, 512-thr blocks -> 4 waves/SIMD.
// R5 POST-MORTEM: converting LDS access to base-pointer arithmetic made the
// compiler lose the LDS addrspace -> flat ops -> 169 us (2.5x regression).
// LESSON: keep direct __shared__ array indexing; make INDICES literal instead.
// R7: revert to R4 body + (a) unroll-2 so buffer index is a literal (safe
// form of R5's intent), (b) 2-tile-deep global prefetch with A/B reg sets:
// FETCH=76MB vs ~36MB ideal -> ~50% L2 miss (~900cy) > 1-tile compute window
// (~700cy) -> per-tile vmcnt stall for all waves. 2 tiles ahead = >=1400cy.
// Barrier discipline identical to R4 (loads hoisted only).
__global__ __launch_bounds__(512) void attn_fwd(const ushort* __restrict__ qh,
                                                const ushort* __restrict__ kc,
                                                const ushort* __restrict__ vt,
                                                ushort* __restrict__ out) {
    __shared__ ushort Ks[2][64][72];   // [buf][key][d]
    __shared__ ushort Vs[2][64][68];   // [buf][d][key-interleaved]
    int tid = threadIdx.x;
    int lane = tid & 63;
    int w = tid >> 6;                  // 0..7
    int l15 = lane & 15;
    int quad = lane >> 4;
    int bh = blockIdx.y;
    int q0 = blockIdx.x * 128 + w * 16;

    const ushort* qp = qh + ((size_t)bh * NTOK + q0 + l15) * 64 + quad * 8;
    bf16x8 qA0 = *(const bf16x8*)qp;
    bf16x8 qA1 = *(const bf16x8*)(qp + 32);

    float lA = 0.0f;
    f32x4 OA[4];
#pragma unroll
    for (int jd = 0; jd < 4; jd++) OA[jd] = (f32x4)0.0f;

    int sr = tid >> 3;                 // 0..63: full K/V row range with 512 thr
    int sc = (tid & 7) * 8;
    // A/B global pointers: A serves even tiles, B odd tiles; each advances 2 tiles
    const ushort* kpA = kc + (size_t)bh * SEQ * 64 + (size_t)sr * 64 + sc;
    const ushort* vpA = vt + (size_t)bh * 64 * SEQ + (size_t)sr * SEQ + sc;
    const ushort* kpB = kpA + 64 * 64;
    const ushort* vpB = vpA + 64;

    // prefetch tiles 0 (A) and 1 (B) into registers
    uint4 rkA = *(const uint4*)kpA;
    uint4 rvA = *(const uint4*)vpA;
    uint4 rkB = *(const uint4*)kpB;
    uint4 rvB = *(const uint4*)vpB;

#define ATT_COMPUTE(P) { \
    f32x4 SA[4]; \
    _Pragma("unroll") for (int j = 0; j < 4; j++) SA[j] = (f32x4)0.0f; \
    __builtin_amdgcn_s_setprio(1); \
    _Pragma("unroll") for (int j = 0; j < 4; j++) { \
        bf16x8 kf = *(const bf16x8*)&Ks[P][j * 16 + l15][quad * 8]; \
        SA[j] = __builtin_amdgcn_mfma_f32_16x16x32_bf16(kf, qA0, SA[j], 0, 0, 0); } \
    _Pragma("unroll") for (int j = 0; j < 4; j++) { \
        bf16x8 kf = *(const bf16x8*)&Ks[P][j * 16 + l15][32 + quad * 8]; \
        SA[j] = __builtin_amdgcn_mfma_f32_16x16x32_bf16(kf, qA1, SA[j], 0, 0, 0); } \
    __builtin_amdgcn_s_setprio(0); \
    _Pragma("unroll") for (int pb2 = 0; pb2 < 2; pb2++) { \
        int j0 = 2 * pb2, j1 = j0 + 1; \
        u32x4 wa; \
        _Pragma("unroll") for (int r = 0; r < 4; r++) { \
            float a0 = __builtin_amdgcn_exp2f(SA[j0][r]); \
            float a1 = __builtin_amdgcn_exp2f(SA[j1][r]); \
            lA += a0 + a1; \
            wa[r] = pack2bf(a0, a1); } \
        bf16x8 pA = __builtin_bit_cast(bf16x8, wa); \
        __builtin_amdgcn_s_setprio(1); \
        _Pragma("unroll") for (int jd = 0; jd < 4; jd++) { \
            bf16x8 vf = *(const bf16x8*)&Vs[P][jd * 16 + l15][pb2 * 32 + quad * 8]; \
            OA[jd] = __builtin_amdgcn_mfma_f32_16x16x32_bf16(vf, pA, OA[jd], 0, 0, 0); } \
        __builtin_amdgcn_s_setprio(0); } }

    for (int tt = 0; tt < NKT; tt += 2) {
        // ---- tile tt (buffer 0, regs A) ----
        *(uint4*)&Ks[0][sr][sc] = rkA;
        *(uint4*)&Vs[0][sr][sc] = rvA;
        if (tt + 2 < NKT) {           // issue tile tt+2 loads ~2 tiles early
            kpA += 2 * 64 * 64; vpA += 2 * 64;
            rkA = *(const uint4*)kpA;
            rvA = *(const uint4*)vpA;
        }
        __syncthreads();
        ATT_COMPUTE(0);
        // ---- tile tt+1 (buffer 1, regs B) ----
        *(uint4*)&Ks[1][sr][sc] = rkB;
        *(uint4*)&Vs[1][sr][sc] = rvB;
        if (tt + 3 < NKT) {           // issue tile tt+3 loads ~2 tiles early
            kpB += 2 * 64 * 64; vpB += 2 * 64;
            rkB = *(const uint4*)kpB;
            rvB = *(const uint4*)vpB;
        }
        __syncthreads();
        ATT_COMPUTE(1);
    }

    lA += __shfl_xor(lA, 16);
    lA += __shfl_xor(lA, 32);
    float invA = 1.0f / lA;
    int b = bh >> 4, h = bh & 15;
    int tokA = (b << 11) + q0 + l15;
    ushort* obaseA = out + ((size_t)tokA * NHEAD + h) * 64;
#pragma unroll
    for (int jd = 0; jd < 4; jd++) {
        u32x2 pk;
        pk.x = pack2bf(OA[jd][0] * invA, OA[jd][1] * invA);
        pk.y = pack2bf(OA[jd][2] * invA, OA[jd][3] * invA);
        *(u32x2*)&obaseA[jd * 16 + quad * 4] = pk;
    }
}

// ---------- launch ----------
extern "C" void kernel_launch(void* const* d_in, const int* in_sizes, int n_in,
                              void* d_out, int out_size, void* d_ws, size_t ws_size,
                              hipStream_t stream) {
    const float* x      = (const float*)d_in[0];
    const float* y      = (const float*)d_in[1];
    const float* qkv_w  = (const float*)d_in[2];
    const float* qkv_b  = (const float*)d_in[3];
    const float* kv_w   = (const float*)d_in[4];
    const float* kv_b   = (const float*)d_in[5];
    const float* qn_w   = (const float*)d_in[6];
    const float* kn_w   = (const float*)d_in[7];
    const float* proj_w = (const float*)d_in[8];
    const float* proj_b = (const float*)d_in[9];
    float* outp = (float*)d_out;

    char* ws = (char*)d_ws;
    ushort* x_bf    = (ushort*)ws; ws += (size_t)TOK_X * CDIM * 2;
    ushort* y_bf    = (ushort*)ws; ws += (size_t)TOK_Y * CDIM * 2;
    ushort* qkvw_bf = (ushort*)ws; ws += (size_t)3 * CDIM * CDIM * 2;
    ushort* kvw_bf  = (ushort*)ws; ws += (size_t)2 * CDIM * CDIM * 2;
    ushort* projw_bf= (ushort*)ws; ws += (size_t)CDIM * CDIM * 2;
    ushort* qh      = (ushort*)ws; ws += (size_t)BHN * NTOK * 64 * 2;
    ushort* kc      = (ushort*)ws; ws += (size_t)BHN * SEQ * 64 * 2;
    ushort* vt      = (ushort*)ws; ws += (size_t)BHN * SEQ * 64 * 2;
    ushort* ao      = (ushort*)ws; ws += (size_t)TOK_X * CDIM * 2;

    int c0 = TOK_X * CDIM / 2048;
    int c1 = c0 + TOK_Y * CDIM / 2048;
    int c2 = c1 + 3 * CDIM * CDIM / 2048;
    int c3 = c2 + 2 * CDIM * CDIM / 2048;
    int c4 = c3 + CDIM * CDIM / 2048;
    cast_all<<<c4, 256, 0, stream>>>(x, x_bf, c0, y, y_bf, c1, qkv_w, qkvw_bf, c2,
                                     kv_w, kvw_bf, c3, proj_w, projw_bf);

    gemm_qkvkv<<<QKV_BLOCKS + KV_BLOCKS, 256, 0, stream>>>(
        x_bf, qkvw_bf, qkv_b, y_bf, kvw_bf, kv_b, qh, kc, vt, qn_w, kn_w);

    attn_fwd<<<dim3(NTOK / 128, BHN), 512, 0, stream>>>(qh, kc, vt, ao);

    gemm_proj<<<512, 256, 0, stream>>>(ao, projw_bf, proj_b, outp);
}

// Round 16
// 217.121 us; speedup vs baseline: 1.4575x; 1.0034x over previous
//
#include <hip/hip_runtime.h>

// ---------- constants for this problem ----------
#define BATCH 2
#define NTOK 2048          // image tokens per batch
#define MTOK 256           // text tokens per batch
#define CDIM 1024
#define NHEAD 16
#define HD 64
#define SEQ (NTOK + MTOK)  // 2304
#define TOK_X (BATCH * NTOK)   // 4096
#define TOK_Y (BATCH * MTOK)   // 512
#define BHN (BATCH * NHEAD)    // 32
#define NKT (SEQ / 64)         // 36 KV tiles (even -> unroll-2 safe)
#define QKV_BLOCKS 1536        // (3*CDIM/64) * (TOK_X/128) = 48*32
#define KV_BLOCKS 128          // (2*CDIM/64) * (TOK_Y/128) = 32*4

typedef __attribute__((ext_vector_type(8))) short bf16x8;
typedef __attribute__((ext_vector_type(4))) short bf16x4;
typedef __attribute__((ext_vector_type(4))) float f32x4;
typedef __attribute__((ext_vector_type(2))) unsigned int u32x2;
typedef __attribute__((ext_vector_type(4))) unsigned int u32x4;
#if __has_builtin(__builtin_amdgcn_cvt_pk_bf16_f32)
typedef __attribute__((ext_vector_type(2))) __bf16 bf16x2_t;
#endif

__device__ __forceinline__ float b2f(ushort u) {
    unsigned v = ((unsigned)u) << 16;
    return __builtin_bit_cast(float, v);
}
__device__ __forceinline__ ushort f2b(float f) {
    unsigned u = __builtin_bit_cast(unsigned, f);
    u += 0x7fffu + ((u >> 16) & 1u);   // round-to-nearest-even
    return (ushort)(u >> 16);
}
__device__ __forceinline__ unsigned pack2bf(float a, float b) {
#if __has_builtin(__builtin_amdgcn_cvt_pk_bf16_f32)
    bf16x2_t h = __builtin_amdgcn_cvt_pk_bf16_f32(a, b);   // lo=a, hi=b
    return __builtin_bit_cast(unsigned, h);
#else
    return ((unsigned)f2b(b) << 16) | (unsigned)f2b(a);
#endif
}

// async 16B global -> LDS; LDS dest = wave-uniform base, HW scatters lane*16B
__device__ __forceinline__ void async_load16(const ushort* g, ushort* l) {
    __builtin_amdgcn_global_load_lds(
        (const __attribute__((address_space(1))) unsigned*)(const void*)g,
        (__attribute__((address_space(3))) unsigned*)(void*)l, 16, 0, 0);
}

// ---------- one merged cast kernel: 5 fp32->bf16 segments ----------
__global__ __launch_bounds__(256) void cast_all(
    const float* __restrict__ s0, ushort* __restrict__ t0, int b0,
    const float* __restrict__ s1, ushort* __restrict__ t1, int b1,
    const float* __restrict__ s2, ushort* __restrict__ t2, int b2,
    const float* __restrict__ s3, ushort* __restrict__ t3, int b3,
    const float* __restrict__ s4, ushort* __restrict__ t4) {
    int blk = blockIdx.x;
    const float* s; ushort* t;
    if (blk < b0)      { s = s0; t = t0; }
    else if (blk < b1) { s = s1; t = t1; blk -= b0; }
    else if (blk < b2) { s = s2; t = t2; blk -= b1; }
    else if (blk < b3) { s = s3; t = t3; blk -= b2; }
    else               { s = s4; t = t4; blk -= b3; }
    int i = (blk * 256 + threadIdx.x) * 8;
    float4 a = *(const float4*)(s + i);
    float4 b = *(const float4*)(s + i + 4);
    ushort tmp[8] = {f2b(a.x), f2b(a.y), f2b(a.z), f2b(a.w),
                     f2b(b.x), f2b(b.y), f2b(b.z), f2b(b.w)};
    *(uint4*)(t + i) = *(const uint4*)tmp;
}

// ---------- merged qkv+kv GEMM, 128x64 tiles, one launch (1664 blocks) ----------
// R16: tile 128(M)x64(N), 4 waves x (32x64), acc[2][4], LDS 24 KB -> 5-6
// blocks/CU co-resident (vs 2-3 at 128x128): the K-loop is latency-bound
// (load -> barrier -> compute, 16 iters), more co-resident blocks = overlap.
// One head per block (N-tile = 64 = one head's d range). Epilogue: bias +
// rmsnorm(q,k) + scatter q->qh, k->kc, V directly into pair-interleaved vt.
__global__ __launch_bounds__(256) void gemm_qkvkv(const ushort* __restrict__ Aq,
                                                  const ushort* __restrict__ Wq,
                                                  const float* __restrict__ bq,
                                                  const ushort* __restrict__ Ak,
                                                  const ushort* __restrict__ Wk,
                                                  const float* __restrict__ bk,
                                                  ushort* __restrict__ d_q,
                                                  ushort* __restrict__ d_k,
                                                  ushort* __restrict__ d_vt,
                                                  const float* __restrict__ qn_w,
                                                  const float* __restrict__ kn_w) {
    __shared__ ushort As[128][64];   // 16 KB
    __shared__ ushort Bs[64][64];    // 8 KB
    int tid = threadIdx.x;
    int lane = tid & 63;
    int w = tid >> 6;
    int wm = w * 32;
    int l15 = lane & 15;
    int quad = lane >> 4;
    int sw = l15 & 7;

    int blk = blockIdx.x;
    int mode, bx, by;
    const ushort *A, *Bt;
    const float* bias;
    if (blk < QKV_BLOCKS) {
        mode = 1;
        int xcd = blk & 7;
        int loc = blk >> 3;         // 0..191
        by = xcd * 4 + (loc & 3);   // 0..31: each XCD a contiguous 4-row M strip
        bx = loc >> 2;              // 0..47
        A = Aq; Bt = Wq; bias = bq;
    } else {
        mode = 2;
        int loc = blk - QKV_BLOCKS; // 0..127
        bx = loc & 31;              // 0..31
        by = loc >> 5;              // 0..3
        A = Ak; Bt = Wk; bias = bk;
    }
    int bm = by * 128;
    int bn = bx * 64;

    f32x4 acc[2][4];
#pragma unroll
    for (int i = 0; i < 2; i++)
#pragma unroll
        for (int j = 0; j < 4; j++) acc[i][j] = (f32x4)0.0f;

    int lrow = lane >> 3;
    int lcol = ((lane & 7) ^ lrow) * 8;

    for (int k0 = 0; k0 < CDIM; k0 += 64) {
        __syncthreads();
#pragma unroll
        for (int p = 0; p < 4; p++) {
            int rb = w * 32 + p * 8;
            async_load16(&A[(size_t)(bm + rb + lrow) * CDIM + k0 + lcol], &As[rb][0]);
        }
#pragma unroll
        for (int p = 0; p < 2; p++) {
            int rb = w * 16 + p * 8;
            async_load16(&Bt[(size_t)(bn + rb + lrow) * CDIM + k0 + lcol], &Bs[rb][0]);
        }
        __syncthreads();
#pragma unroll
        for (int kk = 0; kk < 64; kk += 32) {
            bf16x8 af[2], bfr[4];
            int g = (kk >> 3) + quad;
            int csw = (g ^ sw) * 8;
#pragma unroll
            for (int i = 0; i < 2; i++)
                af[i] = *(const bf16x8*)&As[wm + i * 16 + l15][csw];
#pragma unroll
            for (int j = 0; j < 4; j++)
                bfr[j] = *(const bf16x8*)&Bs[j * 16 + l15][csw];
#pragma unroll
            for (int i = 0; i < 2; i++)
#pragma unroll
                for (int j = 0; j < 4; j++)
                    acc[i][j] = __builtin_amdgcn_mfma_f32_16x16x32_bf16(af[i], bfr[j], acc[i][j], 0, 0, 0);
        }
    }

    float bv[4];
#pragma unroll
    for (int j = 0; j < 4; j++) bv[j] = bias[bn + j * 16 + l15];
#pragma unroll
    for (int i = 0; i < 2; i++)
#pragma unroll
        for (int j = 0; j < 4; j++)
#pragma unroll
            for (int r = 0; r < 4; r++) acc[i][j][r] += bv[j];

    int region = bn >> 10;
    int h = (bn >> 6) & (NHEAD - 1);
    bool is_q = (mode == 1) && (region == 0);
    bool is_k = (mode == 1) ? (region == 1) : (region == 0);
    if (is_q || is_k) {
        const float* wv = is_q ? qn_w : kn_w;
        float wj[4];
#pragma unroll
        for (int j = 0; j < 4; j++) wj[j] = wv[j * 16 + l15];
        float qs = is_q ? (0.125f * 1.44269504088896f) : 1.0f;
#pragma unroll
        for (int i = 0; i < 2; i++)
#pragma unroll
            for (int r = 0; r < 4; r++) {
                float s = acc[i][0][r] * acc[i][0][r] + acc[i][1][r] * acc[i][1][r]
                        + acc[i][2][r] * acc[i][2][r] + acc[i][3][r] * acc[i][3][r];
                s += __shfl_xor(s, 1);
                s += __shfl_xor(s, 2);
                s += __shfl_xor(s, 4);
                s += __shfl_xor(s, 8);
                float rs = rsqrtf(s * (1.0f / 64.0f) + 1e-6f) * qs;
#pragma unroll
                for (int j = 0; j < 4; j++) acc[i][j][r] *= rs * wj[j];
            }
    }
    size_t l15seq = (size_t)l15 * SEQ;   // for v scatter
#pragma unroll
    for (int i = 0; i < 2; i++) {
#pragma unroll
        for (int r = 0; r < 4; r++) {
            int t = bm + wm + i * 16 + quad * 4 + r;   // token row
            int b, s;
            if (mode == 1) { b = t >> 11; s = t & (NTOK - 1); }
            else           { b = t >> 8;  s = NTOK + (t & (MTOK - 1)); }
            size_t bh = (size_t)(b * NHEAD + h);
            if (is_q) {
                size_t base = (bh * NTOK + s) * 64;
#pragma unroll
                for (int j = 0; j < 4; j++)
                    d_q[base + j * 16 + l15] = f2b(acc[i][j][r]);
            } else if (is_k) {
                size_t base = (bh * SEQ + s) * 64;
#pragma unroll
                for (int j = 0; j < 4; j++)
                    d_k[base + j * 16 + l15] = f2b(acc[i][j][r]);
            } else {
                // V -> vt [bh][d][pair-interleaved seq]
                int within = s & 31;
                int pos = ((s >> 5) << 5) + ((within & 15) << 1) + (within >> 4);
                size_t base = bh * 64 * SEQ + l15seq + pos;
#pragma unroll
                for (int j = 0; j < 4; j++)
                    d_vt[base + (size_t)(j * 16) * SEQ] = f2b(acc[i][j][r]);
            }
        }
    }
}

// ---------- proj GEMM: 128x64 tiles, fp32 out + bias (XCD-swizzled grid 512) ----------
__global__ __launch_bounds__(256) void gemm_proj(const ushort* __restrict__ A,
                                                 const ushort* __restrict__ Bt,
                                                 const float* __restrict__ bias,
                                                 float* __restrict__ Cf) {
    __shared__ ushort As[128][64];
    __shared__ ushort Bs[64][64];
    int tid = threadIdx.x;
    int lane = tid & 63;
    int w = tid >> 6;
    int wm = w * 32;
    int l15 = lane & 15;
    int quad = lane >> 4;
    int sw = l15 & 7;
    int xcd = blockIdx.x & 7;
    int loc = blockIdx.x >> 3;      // 0..63
    int by = xcd * 4 + (loc & 3);   // 0..31
    int bx = loc >> 2;              // 0..15
    int bm = by * 128;
    int bn = bx * 64;

    f32x4 acc[2][4];
#pragma unroll
    for (int i = 0; i < 2; i++)
#pragma unroll
        for (int j = 0; j < 4; j++) acc[i][j] = (f32x4)0.0f;

    int lrow = lane >> 3;
    int lcol = ((lane & 7) ^ lrow) * 8;

    for (int k0 = 0; k0 < CDIM; k0 += 64) {
        __syncthreads();
#pragma unroll
        for (int p = 0; p < 4; p++) {
            int rb = w * 32 + p * 8;
            async_load16(&A[(size_t)(bm + rb + lrow) * CDIM + k0 + lcol], &As[rb][0]);
        }
#pragma unroll
        for (int p = 0; p < 2; p++) {
            int rb = w * 16 + p * 8;
            async_load16(&Bt[(size_t)(bn + rb + lrow) * CDIM + k0 + lcol], &Bs[rb][0]);
        }
        __syncthreads();
#pragma unroll
        for (int kk = 0; kk < 64; kk += 32) {
            bf16x8 af[2], bfr[4];
            int g = (kk >> 3) + quad;
            int csw = (g ^ sw) * 8;
#pragma unroll
            for (int i = 0; i < 2; i++)
                af[i] = *(const bf16x8*)&As[wm + i * 16 + l15][csw];
#pragma unroll
            for (int j = 0; j < 4; j++)
                bfr[j] = *(const bf16x8*)&Bs[j * 16 + l15][csw];
#pragma unroll
            for (int i = 0; i < 2; i++)
#pragma unroll
                for (int j = 0; j < 4; j++)
                    acc[i][j] = __builtin_amdgcn_mfma_f32_16x16x32_bf16(af[i], bfr[j], acc[i][j], 0, 0, 0);
        }
    }
#pragma unroll
    for (int i = 0; i < 2; i++) {
        int row0 = bm + wm + i * 16 + quad * 4;
#pragma unroll
        for (int j = 0; j < 4; j++) {
            int col = bn + j * 16 + l15;
            float bvv = bias[col];
#pragma unroll
            for (int r = 0; r < 4; r++)
                Cf[(size_t)(row0 + r) * CDIM + col] = acc[i][j][r] + bvv;
        }
    }
}

// ---------- flash attention: 16 q/wave, 8 waves/block, 64-key dbuf tiles ----------
// R4 (67.1 us): 16q/wave, 512-thr blocks -> 4 waves/SIMD.
// R5 POST-MORTEM: LDS base-pointer arithmetic -> flat ops -> 169 us. LESSON:
// keep direct __shared__ indexing; make INDICES literal.
// R7 (63.7 us): unroll-2 literal buffer index + 2-tile-deep A/B reg prefetch.
// R10: fold softmax denominator into the matrix pipe. Counters: MfmaUtil
// 24.7 / VALUBusy 48.9 (2:1 = instruction-mix ratio) -> near issue-bound,
// VALU-heavy. The lA accumulation was 16 serial v_add/tile + 2 end shfls;
// replace with one all-ones-A MFMA per pb2 half: D[i][q] = sum_k P[k][q]
// (K=32 spans the half-tile across all lanes' B fragments; rows/quads get
// identical copies -> Lacc[0] is the complete per-q sum, no reduction).
// Sum is now over the same bf16-rounded P that PV consumes (consistent).
__global__ __launch_bounds__(512) void attn_fwd(const ushort* __restrict__ qh,
                                                const ushort* __restrict__ kc,
                                                const ushort* __restrict__ vt,
                                                ushort* __restrict__ out) {
    __shared__ ushort Ks[2][64][72];   // [buf][key][d]
    __shared__ ushort Vs[2][64][68];   // [buf][d][key-interleaved]
    int tid = threadIdx.x;
    int lane = tid & 63;
    int w = tid >> 6;                  // 0..7
    int l15 = lane & 15;
    int quad = lane >> 4;
    int bh = blockIdx.y;
    int q0 = blockIdx.x * 128 + w * 16;

    const ushort* qp = qh + ((size_t)bh * NTOK + q0 + l15) * 64 + quad * 8;
    bf16x8 qA0 = *(const bf16x8*)qp;
    bf16x8 qA1 = *(const bf16x8*)(qp + 32);

    // all-ones bf16 A-fragment for the denominator MFMA
    u32x4 onesw;
    onesw[0] = onesw[1] = onesw[2] = onesw[3] = 0x3F803F80u;
    bf16x8 onesf = __builtin_bit_cast(bf16x8, onesw);

    f32x4 Lacc = (f32x4)0.0f;          // [0] = sum_k P[k][q=l15], quad-uniform
    f32x4 OA[4];
#pragma unroll
    for (int jd = 0; jd < 4; jd++) OA[jd] = (f32x4)0.0f;

    int sr = tid >> 3;                 // 0..63: full K/V row range with 512 thr
    int sc = (tid & 7) * 8;
    // A/B global pointers: A serves even tiles, B odd tiles; each advances 2 tiles
    const ushort* kpA = kc + (size_t)bh * SEQ * 64 + (size_t)sr * 64 + sc;
    const ushort* vpA = vt + (size_t)bh * 64 * SEQ + (size_t)sr * SEQ + sc;
    const ushort* kpB = kpA + 64 * 64;
    const ushort* vpB = vpA + 64;

    // prefetch tiles 0 (A) and 1 (B) into registers
    uint4 rkA = *(const uint4*)kpA;
    uint4 rvA = *(const uint4*)vpA;
    uint4 rkB = *(const uint4*)kpB;
    uint4 rvB = *(const uint4*)vpB;

#define ATT_COMPUTE(P) { \
    f32x4 SA[4]; \
    _Pragma("unroll") for (int j = 0; j < 4; j++) SA[j] = (f32x4)0.0f; \
    __builtin_amdgcn_s_setprio(1); \
    _Pragma("unroll") for (int j = 0; j < 4; j++) { \
        bf16x8 kf = *(const bf16x8*)&Ks[P][j * 16 + l15][quad * 8]; \
        SA[j] = __builtin_amdgcn_mfma_f32_16x16x32_bf16(kf, qA0, SA[j], 0, 0, 0); } \
    _Pragma("unroll") for (int j = 0; j < 4; j++) { \
        bf16x8 kf = *(const bf16x8*)&Ks[P][j * 16 + l15][32 + quad * 8]; \
        SA[j] = __builtin_amdgcn_mfma_f32_16x16x32_bf16(kf, qA1, SA[j], 0, 0, 0); } \
    __builtin_amdgcn_s_setprio(0); \
    _Pragma("unroll") for (int pb2 = 0; pb2 < 2; pb2++) { \
        int j0 = 2 * pb2, j1 = j0 + 1; \
        u32x4 wa; \
        _Pragma("unroll") for (int r = 0; r < 4; r++) { \
            float a0 = __builtin_amdgcn_exp2f(SA[j0][r]); \
            float a1 = __builtin_amdgcn_exp2f(SA[j1][r]); \
            wa[r] = pack2bf(a0, a1); } \
        bf16x8 pA = __builtin_bit_cast(bf16x8, wa); \
        __builtin_amdgcn_s_setprio(1); \
        Lacc = __builtin_amdgcn_mfma_f32_16x16x32_bf16(onesf, pA, Lacc, 0, 0, 0); \
        _Pragma("unroll") for (int jd = 0; jd < 4; jd++) { \
            bf16x8 vf = *(const bf16x8*)&Vs[P][jd * 16 + l15][pb2 * 32 + quad * 8]; \
            OA[jd] = __builtin_amdgcn_mfma_f32_16x16x32_bf16(vf, pA, OA[jd], 0, 0, 0); } \
        __builtin_amdgcn_s_setprio(0); } }

    for (int tt = 0; tt < NKT; tt += 2) {
        // ---- tile tt (buffer 0, regs A) ----
        *(uint4*)&Ks[0][sr][sc] = rkA;
        *(uint4*)&Vs[0][sr][sc] = rvA;
        if (tt + 2 < NKT) {           // issue tile tt+2 loads ~2 tiles early
            kpA += 2 * 64 * 64; vpA += 2 * 64;
            rkA = *(const uint4*)kpA;
            rvA = *(const uint4*)vpA;
        }
        __syncthreads();
        ATT_COMPUTE(0);
        // ---- tile tt+1 (buffer 1, regs B) ----
        *(uint4*)&Ks[1][sr][sc] = rkB;
        *(uint4*)&Vs[1][sr][sc] = rvB;
        if (tt + 3 < NKT) {           // issue tile tt+3 loads ~2 tiles early
            kpB += 2 * 64 * 64; vpB += 2 * 64;
            rkB = *(const uint4*)kpB;
            rvB = *(const uint4*)vpB;
        }
        __syncthreads();
        ATT_COMPUTE(1);
    }

    float invA = 1.0f / Lacc[0];       // complete sum: no cross-lane reduce needed
    int b = bh >> 4, h = bh & 15;
    int tokA = (b << 11) + q0 + l15;
    ushort* obaseA = out + ((size_t)tokA * NHEAD + h) * 64;
#pragma unroll
    for (int jd = 0; jd < 4; jd++) {
        u32x2 pk;
        pk.x = pack2bf(OA[jd][0] * invA, OA[jd][1] * invA);
        pk.y = pack2bf(OA[jd][2] * invA, OA[jd][3] * invA);
        *(u32x2*)&obaseA[jd * 16 + quad * 4] = pk;
    }
}

// ---------- launch ----------
extern "C" void kernel_launch(void* const* d_in, const int* in_sizes, int n_in,
                              void* d_out, int out_size, void* d_ws, size_t ws_size,
                              hipStream_t stream) {
    const float* x      = (const float*)d_in[0];
    const float* y      = (const float*)d_in[1];
    const float* qkv_w  = (const float*)d_in[2];
    const float* qkv_b  = (const float*)d_in[3];
    const float* kv_w   = (const float*)d_in[4];
    const float* kv_b   = (const float*)d_in[5];
    const float* qn_w   = (const float*)d_in[6];
    const float* kn_w   = (const float*)d_in[7];
    const float* proj_w = (const float*)d_in[8];
    const float* proj_b = (const float*)d_in[9];
    float* outp = (float*)d_out;

    char* ws = (char*)d_ws;
    ushort* x_bf    = (ushort*)ws; ws += (size_t)TOK_X * CDIM * 2;
    ushort* y_bf    = (ushort*)ws; ws += (size_t)TOK_Y * CDIM * 2;
    ushort* qkvw_bf = (ushort*)ws; ws += (size_t)3 * CDIM * CDIM * 2;
    ushort* kvw_bf  = (ushort*)ws; ws += (size_t)2 * CDIM * CDIM * 2;
    ushort* projw_bf= (ushort*)ws; ws += (size_t)CDIM * CDIM * 2;
    ushort* qh      = (ushort*)ws; ws += (size_t)BHN * NTOK * 64 * 2;
    ushort* kc      = (ushort*)ws; ws += (size_t)BHN * SEQ * 64 * 2;
    ushort* vt      = (ushort*)ws; ws += (size_t)BHN * SEQ * 64 * 2;
    ushort* ao      = (ushort*)ws; ws += (size_t)TOK_X * CDIM * 2;

    int c0 = TOK_X * CDIM / 2048;
    int c1 = c0 + TOK_Y * CDIM / 2048;
    int c2 = c1 + 3 * CDIM * CDIM / 2048;
    int c3 = c2 + 2 * CDIM * CDIM / 2048;
    int c4 = c3 + CDIM * CDIM / 2048;
    cast_all<<<c4, 256, 0, stream>>>(x, x_bf, c0, y, y_bf, c1, qkv_w, qkvw_bf, c2,
                                     kv_w, kvw_bf, c3, proj_w, projw_bf);

    gemm_qkvkv<<<QKV_BLOCKS + KV_BLOCKS, 256, 0, stream>>>(
        x_bf, qkvw_bf, qkv_b, y_bf, kvw_bf, kv_b, qh, kc, vt, qn_w, kn_w);

    attn_fwd<<<dim3(NTOK / 128, BHN), 512, 0, stream>>>(qh, kc, vt, ao);

    gemm_proj<<<512, 256, 0, stream>>>(ao, projw_bf, proj_b, outp);
}

// Round 17
// 212.283 us; speedup vs baseline: 1.4907x; 1.0228x over previous
//
#include <hip/hip_runtime.h>

// ---------- constants for this problem ----------
#define BATCH 2
#define NTOK 2048          // image tokens per batch
#define MTOK 256           // text tokens per batch
#define CDIM 1024
#define NHEAD 16
#define HD 64
#define SEQ (NTOK + MTOK)  // 2304
#define TOK_X (BATCH * NTOK)   // 4096
#define TOK_Y (BATCH * MTOK)   // 512
#define BHN (BATCH * NHEAD)    // 32
#define NKT (SEQ / 64)         // 36 KV tiles (even -> unroll-2 safe)
#define QKV_BLOCKS 1536        // (3*CDIM/64) * (TOK_X/128) = 48*32
#define KV_BLOCKS 128          // (2*CDIM/64) * (TOK_Y/128) = 32*4

typedef __attribute__((ext_vector_type(8))) short bf16x8;
typedef __attribute__((ext_vector_type(4))) short bf16x4;
typedef __attribute__((ext_vector_type(4))) float f32x4;
typedef __attribute__((ext_vector_type(2))) unsigned int u32x2;
typedef __attribute__((ext_vector_type(4))) unsigned int u32x4;
#if __has_builtin(__builtin_amdgcn_cvt_pk_bf16_f32)
typedef __attribute__((ext_vector_type(2))) __bf16 bf16x2_t;
#endif

__device__ __forceinline__ float b2f(ushort u) {
    unsigned v = ((unsigned)u) << 16;
    return __builtin_bit_cast(float, v);
}
__device__ __forceinline__ ushort f2b(float f) {
    unsigned u = __builtin_bit_cast(unsigned, f);
    u += 0x7fffu + ((u >> 16) & 1u);   // round-to-nearest-even
    return (ushort)(u >> 16);
}
__device__ __forceinline__ unsigned pack2bf(float a, float b) {
#if __has_builtin(__builtin_amdgcn_cvt_pk_bf16_f32)
    bf16x2_t h = __builtin_amdgcn_cvt_pk_bf16_f32(a, b);   // lo=a, hi=b
    return __builtin_bit_cast(unsigned, h);
#else
    return ((unsigned)f2b(b) << 16) | (unsigned)f2b(a);
#endif
}

// async 16B global -> LDS; LDS dest = wave-uniform base, HW scatters lane*16B
__device__ __forceinline__ void async_load16(const ushort* g, ushort* l) {
    __builtin_amdgcn_global_load_lds(
        (const __attribute__((address_space(1))) unsigned*)(const void*)g,
        (__attribute__((address_space(3))) unsigned*)(void*)l, 16, 0, 0);
}

// ---------- one merged cast kernel: 5 fp32->bf16 segments ----------
__global__ __launch_bounds__(256) void cast_all(
    const float* __restrict__ s0, ushort* __restrict__ t0, int b0,
    const float* __restrict__ s1, ushort* __restrict__ t1, int b1,
    const float* __restrict__ s2, ushort* __restrict__ t2, int b2,
    const float* __restrict__ s3, ushort* __restrict__ t3, int b3,
    const float* __restrict__ s4, ushort* __restrict__ t4) {
    int blk = blockIdx.x;
    const float* s; ushort* t;
    if (blk < b0)      { s = s0; t = t0; }
    else if (blk < b1) { s = s1; t = t1; blk -= b0; }
    else if (blk < b2) { s = s2; t = t2; blk -= b1; }
    else if (blk < b3) { s = s3; t = t3; blk -= b2; }
    else               { s = s4; t = t4; blk -= b3; }
    int i = (blk * 256 + threadIdx.x) * 8;
    float4 a = *(const float4*)(s + i);
    float4 b = *(const float4*)(s + i + 4);
    ushort tmp[8] = {f2b(a.x), f2b(a.y), f2b(a.z), f2b(a.w),
                     f2b(b.x), f2b(b.y), f2b(b.z), f2b(b.w)};
    *(uint4*)(t + i) = *(const uint4*)tmp;
}

// ---------- merged qkv+kv GEMM, 128x64 tiles, one launch (1664 blocks) ----------
// R16: tile 128(M)x64(N), 4 waves x (32x64), acc[2][4], LDS 24 KB -> 5-6
// blocks/CU co-resident (vs 2-3 at 128x128): the K-loop is latency-bound
// (load -> barrier -> compute, 16 iters), more co-resident blocks = overlap.
// One head per block (N-tile = 64 = one head's d range). Epilogue: bias +
// rmsnorm(q,k) + scatter q->qh, k->kc, V directly into pair-interleaved vt.
__global__ __launch_bounds__(256) void gemm_qkvkv(const ushort* __restrict__ Aq,
                                                  const ushort* __restrict__ Wq,
                                                  const float* __restrict__ bq,
                                                  const ushort* __restrict__ Ak,
                                                  const ushort* __restrict__ Wk,
                                                  const float* __restrict__ bk,
                                                  ushort* __restrict__ d_q,
                                                  ushort* __restrict__ d_k,
                                                  ushort* __restrict__ d_vt,
                                                  const float* __restrict__ qn_w,
                                                  const float* __restrict__ kn_w) {
    __shared__ ushort As[128][64];   // 16 KB
    __shared__ ushort Bs[64][64];    // 8 KB
    int tid = threadIdx.x;
    int lane = tid & 63;
    int w = tid >> 6;
    int wm = w * 32;
    int l15 = lane & 15;
    int quad = lane >> 4;
    int sw = l15 & 7;

    int blk = blockIdx.x;
    int mode, bx, by;
    const ushort *A, *Bt;
    const float* bias;
    if (blk < QKV_BLOCKS) {
        mode = 1;
        int xcd = blk & 7;
        int loc = blk >> 3;         // 0..191
        by = xcd * 4 + (loc & 3);   // 0..31: each XCD a contiguous 4-row M strip
        bx = loc >> 2;              // 0..47
        A = Aq; Bt = Wq; bias = bq;
    } else {
        mode = 2;
        int loc = blk - QKV_BLOCKS; // 0..127
        bx = loc & 31;              // 0..31
        by = loc >> 5;              // 0..3
        A = Ak; Bt = Wk; bias = bk;
    }
    int bm = by * 128;
    int bn = bx * 64;

    f32x4 acc[2][4];
#pragma unroll
    for (int i = 0; i < 2; i++)
#pragma unroll
        for (int j = 0; j < 4; j++) acc[i][j] = (f32x4)0.0f;

    int lrow = lane >> 3;
    int lcol = ((lane & 7) ^ lrow) * 8;

    for (int k0 = 0; k0 < CDIM; k0 += 64) {
        __syncthreads();
#pragma unroll
        for (int p = 0; p < 4; p++) {
            int rb = w * 32 + p * 8;
            async_load16(&A[(size_t)(bm + rb + lrow) * CDIM + k0 + lcol], &As[rb][0]);
        }
#pragma unroll
        for (int p = 0; p < 2; p++) {
            int rb = w * 16 + p * 8;
            async_load16(&Bt[(size_t)(bn + rb + lrow) * CDIM + k0 + lcol], &Bs[rb][0]);
        }
        __syncthreads();
#pragma unroll
        for (int kk = 0; kk < 64; kk += 32) {
            bf16x8 af[2], bfr[4];
            int g = (kk >> 3) + quad;
            int csw = (g ^ sw) * 8;
#pragma unroll
            for (int i = 0; i < 2; i++)
                af[i] = *(const bf16x8*)&As[wm + i * 16 + l15][csw];
#pragma unroll
            for (int j = 0; j < 4; j++)
                bfr[j] = *(const bf16x8*)&Bs[j * 16 + l15][csw];
#pragma unroll
            for (int i = 0; i < 2; i++)
#pragma unroll
                for (int j = 0; j < 4; j++)
                    acc[i][j] = __builtin_amdgcn_mfma_f32_16x16x32_bf16(af[i], bfr[j], acc[i][j], 0, 0, 0);
        }
    }

    float bv[4];
#pragma unroll
    for (int j = 0; j < 4; j++) bv[j] = bias[bn + j * 16 + l15];
#pragma unroll
    for (int i = 0; i < 2; i++)
#pragma unroll
        for (int j = 0; j < 4; j++)
#pragma unroll
            for (int r = 0; r < 4; r++) acc[i][j][r] += bv[j];

    int region = bn >> 10;
    int h = (bn >> 6) & (NHEAD - 1);
    bool is_q = (mode == 1) && (region == 0);
    bool is_k = (mode == 1) ? (region == 1) : (region == 0);
    if (is_q || is_k) {
        const float* wv = is_q ? qn_w : kn_w;
        float wj[4];
#pragma unroll
        for (int j = 0; j < 4; j++) wj[j] = wv[j * 16 + l15];
        float qs = is_q ? (0.125f * 1.44269504088896f) : 1.0f;
#pragma unroll
        for (int i = 0; i < 2; i++)
#pragma unroll
            for (int r = 0; r < 4; r++) {
                float s = acc[i][0][r] * acc[i][0][r] + acc[i][1][r] * acc[i][1][r]
                        + acc[i][2][r] * acc[i][2][r] + acc[i][3][r] * acc[i][3][r];
                s += __shfl_xor(s, 1);
                s += __shfl_xor(s, 2);
                s += __shfl_xor(s, 4);
                s += __shfl_xor(s, 8);
                float rs = rsqrtf(s * (1.0f / 64.0f) + 1e-6f) * qs;
#pragma unroll
                for (int j = 0; j < 4; j++) acc[i][j][r] *= rs * wj[j];
            }
    }
    size_t l15seq = (size_t)l15 * SEQ;   // for v scatter
#pragma unroll
    for (int i = 0; i < 2; i++) {
#pragma unroll
        for (int r = 0; r < 4; r++) {
            int t = bm + wm + i * 16 + quad * 4 + r;   // token row
            int b, s;
            if (mode == 1) { b = t >> 11; s = t & (NTOK - 1); }
            else           { b = t >> 8;  s = NTOK + (t & (MTOK - 1)); }
            size_t bh = (size_t)(b * NHEAD + h);
            if (is_q) {
                size_t base = (bh * NTOK + s) * 64;
#pragma unroll
                for (int j = 0; j < 4; j++)
                    d_q[base + j * 16 + l15] = f2b(acc[i][j][r]);
            } else if (is_k) {
                size_t base = (bh * SEQ + s) * 64;
#pragma unroll
                for (int j = 0; j < 4; j++)
                    d_k[base + j * 16 + l15] = f2b(acc[i][j][r]);
            } else {
                // V -> vt [bh][d][pair-interleaved seq]
                int within = s & 31;
                int pos = ((s >> 5) << 5) + ((within & 15) << 1) + (within >> 4);
                size_t base = bh * 64 * SEQ + l15seq + pos;
#pragma unroll
                for (int j = 0; j < 4; j++)
                    d_vt[base + (size_t)(j * 16) * SEQ] = f2b(acc[i][j][r]);
            }
        }
    }
}

// ---------- proj GEMM: 128x64 tiles, fp32 out + bias (XCD-swizzled grid 512) ----------
__global__ __launch_bounds__(256) void gemm_proj(const ushort* __restrict__ A,
                                                 const ushort* __restrict__ Bt,
                                                 const float* __restrict__ bias,
                                                 float* __restrict__ Cf) {
    __shared__ ushort As[128][64];
    __shared__ ushort Bs[64][64];
    int tid = threadIdx.x;
    int lane = tid & 63;
    int w = tid >> 6;
    int wm = w * 32;
    int l15 = lane & 15;
    int quad = lane >> 4;
    int sw = l15 & 7;
    int xcd = blockIdx.x & 7;
    int loc = blockIdx.x >> 3;      // 0..63
    int by = xcd * 4 + (loc & 3);   // 0..31
    int bx = loc >> 2;              // 0..15
    int bm = by * 128;
    int bn = bx * 64;

    f32x4 acc[2][4];
#pragma unroll
    for (int i = 0; i < 2; i++)
#pragma unroll
        for (int j = 0; j < 4; j++) acc[i][j] = (f32x4)0.0f;

    int lrow = lane >> 3;
    int lcol = ((lane & 7) ^ lrow) * 8;

    for (int k0 = 0; k0 < CDIM; k0 += 64) {
        __syncthreads();
#pragma unroll
        for (int p = 0; p < 4; p++) {
            int rb = w * 32 + p * 8;
            async_load16(&A[(size_t)(bm + rb + lrow) * CDIM + k0 + lcol], &As[rb][0]);
        }
#pragma unroll
        for (int p = 0; p < 2; p++) {
            int rb = w * 16 + p * 8;
            async_load16(&Bt[(size_t)(bn + rb + lrow) * CDIM + k0 + lcol], &Bs[rb][0]);
        }
        __syncthreads();
#pragma unroll
        for (int kk = 0; kk < 64; kk += 32) {
            bf16x8 af[2], bfr[4];
            int g = (kk >> 3) + quad;
            int csw = (g ^ sw) * 8;
#pragma unroll
            for (int i = 0; i < 2; i++)
                af[i] = *(const bf16x8*)&As[wm + i * 16 + l15][csw];
#pragma unroll
            for (int j = 0; j < 4; j++)
                bfr[j] = *(const bf16x8*)&Bs[j * 16 + l15][csw];
#pragma unroll
            for (int i = 0; i < 2; i++)
#pragma unroll
                for (int j = 0; j < 4; j++)
                    acc[i][j] = __builtin_amdgcn_mfma_f32_16x16x32_bf16(af[i], bfr[j], acc[i][j], 0, 0, 0);
        }
    }
#pragma unroll
    for (int i = 0; i < 2; i++) {
        int row0 = bm + wm + i * 16 + quad * 4;
#pragma unroll
        for (int j = 0; j < 4; j++) {
            int col = bn + j * 16 + l15;
            float bvv = bias[col];
#pragma unroll
            for (int r = 0; r < 4; r++)
                Cf[(size_t)(row0 + r) * CDIM + col] = acc[i][j][r] + bvv;
        }
    }
}

// ---------- flash attention: 16 q/wave, 8 waves/block, 64-key dbuf tiles ----------
// R4 (67.1 us): 16q/wave, 512-thr blocks -> 4 waves/SIMD.
// R5 POST-MORTEM: LDS base-pointer arithmetic -> flat ops -> 169 us. LESSON:
// keep direct __shared__ indexing; make INDICES literal.
// R7 (63.7 us): unroll-2 literal buffer index + 2-tile-deep A/B reg prefetch.
// R10 (60.0 us): denominator via all-ones-A MFMA (VALUBusy 49->43,
// MfmaUtil 25->29; matched prediction).
// R16: Vs pad 68 -> 72. Audit of the 4.7M SQ_LDS_BANK_CONFLICT: Ks rows
// (144B) are 16B-aligned and its read pattern (l15*9+quad)%8 already hits
// the 8-lanes-per-slot minimum, but Vs rows (136B) put odd rows at 8B
// alignment -> every V ds_read/write_b128 on an odd row straddles two 16B
// bank slots. 72 ushorts = 144B rows: aligned, slot = (row+quad+4*pb2)%8
// even spread. One-line change; LDS 35.8->36.9 KB, still 2 blocks/CU.
__global__ __launch_bounds__(512) void attn_fwd(const ushort* __restrict__ qh,
                                                const ushort* __restrict__ kc,
                                                const ushort* __restrict__ vt,
                                                ushort* __restrict__ out) {
    __shared__ ushort Ks[2][64][72];   // [buf][key][d]
    __shared__ ushort Vs[2][64][72];   // [buf][d][key-interleaved]
    int tid = threadIdx.x;
    int lane = tid & 63;
    int w = tid >> 6;                  // 0..7
    int l15 = lane & 15;
    int quad = lane >> 4;
    int bh = blockIdx.y;
    int q0 = blockIdx.x * 128 + w * 16;

    const ushort* qp = qh + ((size_t)bh * NTOK + q0 + l15) * 64 + quad * 8;
    bf16x8 qA0 = *(const bf16x8*)qp;
    bf16x8 qA1 = *(const bf16x8*)(qp + 32);

    // all-ones bf16 A-fragment for the denominator MFMA
    u32x4 onesw;
    onesw[0] = onesw[1] = onesw[2] = onesw[3] = 0x3F803F80u;
    bf16x8 onesf = __builtin_bit_cast(bf16x8, onesw);

    f32x4 Lacc = (f32x4)0.0f;          // [0] = sum_k P[k][q=l15], quad-uniform
    f32x4 OA[4];
#pragma unroll
    for (int jd = 0; jd < 4; jd++) OA[jd] = (f32x4)0.0f;

    int sr = tid >> 3;                 // 0..63: full K/V row range with 512 thr
    int sc = (tid & 7) * 8;
    // A/B global pointers: A serves even tiles, B odd tiles; each advances 2 tiles
    const ushort* kpA = kc + (size_t)bh * SEQ * 64 + (size_t)sr * 64 + sc;
    const ushort* vpA = vt + (size_t)bh * 64 * SEQ + (size_t)sr * SEQ + sc;
    const ushort* kpB = kpA + 64 * 64;
    const ushort* vpB = vpA + 64;

    // prefetch tiles 0 (A) and 1 (B) into registers
    uint4 rkA = *(const uint4*)kpA;
    uint4 rvA = *(const uint4*)vpA;
    uint4 rkB = *(const uint4*)kpB;
    uint4 rvB = *(const uint4*)vpB;

#define ATT_COMPUTE(P) { \
    f32x4 SA[4]; \
    _Pragma("unroll") for (int j = 0; j < 4; j++) SA[j] = (f32x4)0.0f; \
    __builtin_amdgcn_s_setprio(1); \
    _Pragma("unroll") for (int j = 0; j < 4; j++) { \
        bf16x8 kf = *(const bf16x8*)&Ks[P][j * 16 + l15][quad * 8]; \
        SA[j] = __builtin_amdgcn_mfma_f32_16x16x32_bf16(kf, qA0, SA[j], 0, 0, 0); } \
    _Pragma("unroll") for (int j = 0; j < 4; j++) { \
        bf16x8 kf = *(const bf16x8*)&Ks[P][j * 16 + l15][32 + quad * 8]; \
        SA[j] = __builtin_amdgcn_mfma_f32_16x16x32_bf16(kf, qA1, SA[j], 0, 0, 0); } \
    __builtin_amdgcn_s_setprio(0); \
    _Pragma("unroll") for (int pb2 = 0; pb2 < 2; pb2++) { \
        int j0 = 2 * pb2, j1 = j0 + 1; \
        u32x4 wa; \
        _Pragma("unroll") for (int r = 0; r < 4; r++) { \
            float a0 = __builtin_amdgcn_exp2f(SA[j0][r]); \
            float a1 = __builtin_amdgcn_exp2f(SA[j1][r]); \
            wa[r] = pack2bf(a0, a1); } \
        bf16x8 pA = __builtin_bit_cast(bf16x8, wa); \
        __builtin_amdgcn_s_setprio(1); \
        Lacc = __builtin_amdgcn_mfma_f32_16x16x32_bf16(onesf, pA, Lacc, 0, 0, 0); \
        _Pragma("unroll") for (int jd = 0; jd < 4; jd++) { \
            bf16x8 vf = *(const bf16x8*)&Vs[P][jd * 16 + l15][pb2 * 32 + quad * 8]; \
            OA[jd] = __builtin_amdgcn_mfma_f32_16x16x32_bf16(vf, pA, OA[jd], 0, 0, 0); } \
        __builtin_amdgcn_s_setprio(0); } }

    for (int tt = 0; tt < NKT; tt += 2) {
        // ---- tile tt (buffer 0, regs A) ----
        *(uint4*)&Ks[0][sr][sc] = rkA;
        *(uint4*)&Vs[0][sr][sc] = rvA;
        if (tt + 2 < NKT) {           // issue tile tt+2 loads ~2 tiles early
            kpA += 2 * 64 * 64; vpA += 2 * 64;
            rkA = *(const uint4*)kpA;
            rvA = *(const uint4*)vpA;
        }
        __syncthreads();
        ATT_COMPUTE(0);
        // ---- tile tt+1 (buffer 1, regs B) ----
        *(uint4*)&Ks[1][sr][sc] = rkB;
        *(uint4*)&Vs[1][sr][sc] = rvB;
        if (tt + 3 < NKT) {           // issue tile tt+3 loads ~2 tiles early
            kpB += 2 * 64 * 64; vpB += 2 * 64;
            rkB = *(const uint4*)kpB;
            rvB = *(const uint4*)vpB;
        }
        __syncthreads();
        ATT_COMPUTE(1);
    }

    float invA = 1.0f / Lacc[0];       // complete sum: no cross-lane reduce needed
    int b = bh >> 4, h = bh & 15;
    int tokA = (b << 11) + q0 + l15;
    ushort* obaseA = out + ((size_t)tokA * NHEAD + h) * 64;
#pragma unroll
    for (int jd = 0; jd < 4; jd++) {
        u32x2 pk;
        pk.x = pack2bf(OA[jd][0] * invA, OA[jd][1] * invA);
        pk.y = pack2bf(OA[jd][2] * invA, OA[jd][3] * invA);
        *(u32x2*)&obaseA[jd * 16 + quad * 4] = pk;
    }
}

// ---------- launch ----------
extern "C" void kernel_launch(void* const* d_in, const int* in_sizes, int n_in,
                              void* d_out, int out_size, void* d_ws, size_t ws_size,
                              hipStream_t stream) {
    const float* x      = (const float*)d_in[0];
    const float* y      = (const float*)d_in[1];
    const float* qkv_w  = (const float*)d_in[2];
    const float* qkv_b  = (const float*)d_in[3];
    const float* kv_w   = (const float*)d_in[4];
    const float* kv_b   = (const float*)d_in[5];
    const float* qn_w   = (const float*)d_in[6];
    const float* kn_w   = (const float*)d_in[7];
    const float* proj_w = (const float*)d_in[8];
    const float* proj_b = (const float*)d_in[9];
    float* outp = (float*)d_out;

    char* ws = (char*)d_ws;
    ushort* x_bf    = (ushort*)ws; ws += (size_t)TOK_X * CDIM * 2;
    ushort* y_bf    = (ushort*)ws; ws += (size_t)TOK_Y * CDIM * 2;
    ushort* qkvw_bf = (ushort*)ws; ws += (size_t)3 * CDIM * CDIM * 2;
    ushort* kvw_bf  = (ushort*)ws; ws += (size_t)2 * CDIM * CDIM * 2;
    ushort* projw_bf= (ushort*)ws; ws += (size_t)CDIM * CDIM * 2;
    ushort* qh      = (ushort*)ws; ws += (size_t)BHN * NTOK * 64 * 2;
    ushort* kc      = (ushort*)ws; ws += (size_t)BHN * SEQ * 64 * 2;
    ushort* vt      = (ushort*)ws; ws += (size_t)BHN * SEQ * 64 * 2;
    ushort* ao      = (ushort*)ws; ws += (size_t)TOK_X * CDIM * 2;

    int c0 = TOK_X * CDIM / 2048;
    int c1 = c0 + TOK_Y * CDIM / 2048;
    int c2 = c1 + 3 * CDIM * CDIM / 2048;
    int c3 = c2 + 2 * CDIM * CDIM / 2048;
    int c4 = c3 + CDIM * CDIM / 2048;
    cast_all<<<c4, 256, 0, stream>>>(x, x_bf, c0, y, y_bf, c1, qkv_w, qkvw_bf, c2,
                                     kv_w, kvw_bf, c3, proj_w, projw_bf);

    gemm_qkvkv<<<QKV_BLOCKS + KV_BLOCKS, 256, 0, stream>>>(
        x_bf, qkvw_bf, qkv_b, y_bf, kvw_bf, kv_b, qh, kc, vt, qn_w, kn_w);

    attn_fwd<<<dim3(NTOK / 128, BHN), 512, 0, stream>>>(qh, kc, vt, ao);

    gemm_proj<<<512, 256, 0, stream>>>(ao, projw_bf, proj_b, outp);
}